// Round 3
// baseline (26386.966 us; speedup 1.0000x reference)
//
#include <hip/hip_runtime.h>
#include <hip/hip_bf16.h>

// Problem: N=128 nodes, T=512, I=32, H=256, 2-layer per-node LSTM + LayerNorm.
// v3: node split across 2 CUs (unit-split), weights fully VGPR-resident,
// per-step 256B h-half exchange via LLC (agent-scope atomics), quad k-split
// with DPP rotate-reduce, swizzled conflict-free hbuf.

typedef _Float16 half2_t __attribute__((ext_vector_type(2)));
typedef _Float16 half8_t __attribute__((ext_vector_type(8)));
typedef float floatx4 __attribute__((ext_vector_type(4)));

__device__ __forceinline__ unsigned pk(float a, float b) {
  half2_t h = { (_Float16)a, (_Float16)b };
  return __builtin_bit_cast(unsigned, h);
}
__device__ __forceinline__ float fdot2(unsigned w, unsigned h, float c) {
  return __builtin_amdgcn_fdot2(__builtin_bit_cast(half2_t, w),
                                __builtin_bit_cast(half2_t, h), c, false);
}
__device__ __forceinline__ float h2f(unsigned short u) {
  return (float)__builtin_bit_cast(_Float16, u);
}
__device__ __forceinline__ unsigned short f2h(float f) {
  return __builtin_bit_cast(unsigned short, (_Float16)f);
}
__device__ __forceinline__ float sigmf(float x) {
  return __builtin_amdgcn_rcpf(1.f + __expf(-x));
}
__device__ __forceinline__ float tanh_(float x) {
  return 2.f * sigmf(2.f * x) - 1.f;
}
__device__ __forceinline__ floatx4 mfma16(half8_t a, half8_t b, floatx4 c) {
  return __builtin_amdgcn_mfma_f32_16x16x32_f16(a, b, c, 0, 0, 0);
}
// DPP quad_perm; ctrl semantics verified by v2 (passed): rotk = value from lane (r-k)&3
template<int CTRL>
__device__ __forceinline__ float dppf(float x) {
  return __builtin_bit_cast(
      float, __builtin_amdgcn_update_dpp(0, __builtin_bit_cast(int, x), CTRL,
                                         0xf, 0xf, true));
}

// ---------------------------------------------------------------------------
// GEMM: C[n][m][g] = sum_k A[n][m][k] * B[n][g][k].
// C stored f16 TRANSPOSED per timestep: C[n][t][unit*4 + gate].
// ---------------------------------------------------------------------------
template<int K, int KT, bool AF16>
__global__ __launch_bounds__(256)
void gemm_xw(const void* __restrict__ Ap, const float* __restrict__ Bp,
             unsigned short* __restrict__ Cp)
{
  __shared__ unsigned short As[128][KT + 8];
  __shared__ unsigned short Bs[128][KT + 8];
  const int tid = threadIdx.x;
  const int node = blockIdx.y;
  const int mt = blockIdx.x >> 3;
  const int nt = blockIdx.x & 7;
  const int lane = tid & 63, wv = tid >> 6;
  const int wr = wv >> 1, wc = wv & 1;
  const int lm = lane & 15, lk = (lane >> 4) * 8;

  floatx4 zero = {0.f, 0.f, 0.f, 0.f};
  floatx4 acc[4][4];
#pragma unroll
  for (int i = 0; i < 4; ++i)
#pragma unroll
    for (int j = 0; j < 4; ++j) acc[i][j] = zero;

  for (int kt = 0; kt < K; kt += KT) {
    if (AF16) {
      const unsigned short* A = (const unsigned short*)Ap + (size_t)node * 512 * K;
      const int CPR = KT / 8;
#pragma unroll
      for (int c = tid; c < 128 * CPR; c += 256) {
        int r = c / CPR, cc = (c % CPR) * 8;
        *(uint4*)&As[r][cc] =
            *(const uint4*)(A + (size_t)(mt * 128 + r) * K + kt + cc);
      }
    } else {
      const float* A = (const float*)Ap + (size_t)node * 512 * K;
      const int CPR = KT / 4;
#pragma unroll
      for (int c = tid; c < 128 * CPR; c += 256) {
        int r = c / CPR, cc = (c % CPR) * 4;
        float4 v = *(const float4*)(A + (size_t)(mt * 128 + r) * K + kt + cc);
        uint2 p = make_uint2(pk(v.x, v.y), pk(v.z, v.w));
        *(uint2*)&As[r][cc] = p;
      }
    }
    {
      const float* B = Bp + (size_t)node * 1024 * K;
      const int CPR = KT / 4;
#pragma unroll
      for (int c = tid; c < 128 * CPR; c += 256) {
        int r = c / CPR, cc = (c % CPR) * 4;
        float4 v = *(const float4*)(B + (size_t)(nt * 128 + r) * K + kt + cc);
        uint2 p = make_uint2(pk(v.x, v.y), pk(v.z, v.w));
        *(uint2*)&Bs[r][cc] = p;
      }
    }
    __syncthreads();
#pragma unroll
    for (int ks = 0; ks < KT / 32; ++ks) {
      half8_t af[4], bf[4];
#pragma unroll
      for (int i = 0; i < 4; ++i)
        af[i] = *(const half8_t*)&As[wr * 64 + i * 16 + lm][ks * 32 + lk];
#pragma unroll
      for (int j = 0; j < 4; ++j)
        bf[j] = *(const half8_t*)&Bs[wc * 64 + j * 16 + lm][ks * 32 + lk];
#pragma unroll
      for (int i = 0; i < 4; ++i)
#pragma unroll
        for (int j = 0; j < 4; ++j)
          acc[i][j] = mfma16(af[i], bf[j], acc[i][j]);
    }
    __syncthreads();
  }
  unsigned short* C = Cp + (size_t)node * 512 * 1024;
#pragma unroll
  for (int i = 0; i < 4; ++i)
#pragma unroll
    for (int j = 0; j < 4; ++j)
#pragma unroll
      for (int rr = 0; rr < 4; ++rr) {
        int row = mt * 128 + wr * 64 + i * 16 + (lane >> 4) * 4 + rr;
        int g   = nt * 128 + wc * 64 + j * 16 + lm;     // gate-row 0..1023
        // transposed: [t][unit*4 + gate]
        C[(size_t)row * 1024 + (g & 255) * 4 + (g >> 8)] = f2h(acc[i][j][rr]);
      }
}

// ---------------------------------------------------------------------------
// lstm_rec v3: grid 256 = 128 nodes x 2 sides, 512 thr (8 waves, 2/SIMD).
// Side s owns units [s*128, s*128+128). Lane quad: r=l&3 = k-quarter & gate.
// Slice j: gate (r+j)&3 of unit u, k in [64r,64r+64) -> 32 dw f16 in VGPR.
// After rotate-reduce lane r holds gate r of unit u; quad broadcasts combine.
// h halves exchanged cross-CU through LLC each step (double-buffered by t&1).
// ---------------------------------------------------------------------------
template<bool WRITE_HS, bool FINAL>
__global__ __launch_bounds__(512, 2)
void lstm_rec(const unsigned short* __restrict__ xW,   // [n][t][u*4+G] f16
              const float* __restrict__ Whh,           // [n][1024][256] fp32
              const float* __restrict__ bih, const float* __restrict__ bhh,
              unsigned short* __restrict__ hs,         // [n][t][256] f16 (layer0)
              const float* __restrict__ gamma, const float* __restrict__ beta,
              float* __restrict__ out,                 // [n][256] fp32 (layer1)
              unsigned* __restrict__ exch,             // [n][2][2][64] dw
              int* __restrict__ flags)                 // [n][2]
{
  __shared__ __align__(16) unsigned hbuf[2][160];      // 4 quarters at 36-dw stride
  __shared__ float red[256];
  __shared__ float redv[2];

  const int tid = threadIdx.x;
  const int node = blockIdx.x & 127;
  const int side = blockIdx.x >> 7;                    // partner = blockIdx.x^128 (same XCD)
  const int l = tid & 63, w = tid >> 6;
  const int r = l & 3;
  const int ul = w * 16 + (l >> 2);                    // local unit 0..127
  const int u = side * 128 + ul;                       // global unit

  const float bias = bih[node * 1024 + r * 256 + u] + bhh[node * 1024 + r * 256 + u];

  // ---- weights: 128 dw f16, fully VGPR-resident ----
  unsigned wv[128];
#pragma unroll
  for (int j = 0; j < 4; ++j) {
    const int row = (((r + j) & 3) << 8) + u;
    const float4* Wp =
        (const float4*)(Whh + ((size_t)node * 1024 + row) * 256 + 64 * r);
#pragma unroll
    for (int m = 0; m < 16; ++m) {
      float4 v = Wp[m];
      wv[j * 32 + 2 * m]     = pk(v.x, v.y);
      wv[j * 32 + 2 * m + 1] = pk(v.z, v.w);
    }
  }

  if (tid < 160) hbuf[0][tid] = 0;
  float c = 0.f, hl = 0.f;
  const unsigned short* xwp = xW + (size_t)node * 512 * 1024;
  int* ofl = flags + node * 2 + side;
  int* pfl = flags + node * 2 + (1 - side);
  unsigned* oex = exch + (node * 2 + side) * 2 * 64;
  unsigned* pex = exch + (node * 2 + (1 - side)) * 2 * 64;
  int dead = 0;
  __syncthreads();

  for (int t = 0; t < 512; ++t) {
    const int p = t & 1, np = p ^ 1;
    unsigned short xu = xwp[t * 1024 + u * 4 + r];     // gate r of unit u

    // own k-quarter of h (16-lane broadcast groups, conflict-free swizzle)
    unsigned hd[32];
    {
      const uint4* hb = (const uint4*)&hbuf[p][r * 36];
#pragma unroll
      for (int m = 0; m < 8; ++m) {
        uint4 q = hb[m];
        hd[4 * m] = q.x; hd[4 * m + 1] = q.y;
        hd[4 * m + 2] = q.z; hd[4 * m + 3] = q.w;
      }
    }

    float a0 = 0.f, a1 = 0.f, a2 = 0.f, a3 = 0.f;
#pragma unroll
    for (int d = 0; d < 32; ++d) {
      a0 = fdot2(wv[d],      hd[d], a0);
      a1 = fdot2(wv[32 + d], hd[d], a1);
      a2 = fdot2(wv[64 + d], hd[d], a2);
      a3 = fdot2(wv[96 + d], hd[d], a3);
    }
    // lane r <- full pre-activation of gate r, unit u
    float A = a0 + dppf<0x93>(a1) + dppf<0x4E>(a2) + dppf<0x39>(a3);
    A += bias + h2f(xu);

    float sg = sigmf(A);
    float th = tanh_(A);
    float act = (r == 2) ? th : sg;                    // gate order i,f,g,o
    float iv = dppf<0x00>(act);
    float fv = dppf<0x55>(act);
    float gv = dppf<0xAA>(act);
    float ov = dppf<0xFF>(act);
    c = fv * c + iv * gv;
    hl = ov * tanh_(c);
    unsigned short hh = f2h(hl);

    if (r == 0) {
      const int q = u >> 6;
      const int dw = q * 36 + ((u & 63) >> 1);
      ((unsigned short*)&hbuf[np][0])[dw * 2 + (u & 1)] = hh;  // own half
      ((volatile unsigned short*)(oex + p * 64))[ul] = hh;     // publish
      if (WRITE_HS) hs[((size_t)node * 512 + t) * 256 + u] = hh;
    }
    __syncthreads();  // drains vmcnt for all waves -> stores in L2
    if (tid == 0)
      __hip_atomic_store(ofl, t + 1, __ATOMIC_RELEASE, __HIP_MEMORY_SCOPE_AGENT);
    if (!dead) {
      int it = 0;
      while (__hip_atomic_load(pfl, __ATOMIC_ACQUIRE, __HIP_MEMORY_SCOPE_AGENT) <= t) {
        if (++it > 65536) { dead = 1; break; }  // anti-hang; wrong-but-terminates
      }
    }
    if (tid < 64) {  // pull partner half (acquire above invalidated caches)
      unsigned v = *(volatile unsigned*)(pex + p * 64 + tid);
      const int pu = (1 - side) * 128 + 2 * tid;
      hbuf[np][(pu >> 6) * 36 + ((pu & 63) >> 1)] = v;
    }
    __syncthreads();
  }

  if (FINAL) {
    // full h(511) sits in hbuf[0]
    float hv = 0.f;
    if (tid < 256) {
      unsigned v = hbuf[0][(tid >> 6) * 36 + ((tid & 63) >> 1)];
      unsigned short us = (tid & 1) ? (unsigned short)(v >> 16)
                                    : (unsigned short)(v & 0xffff);
      hv = h2f(us);
      red[tid] = hv;
    }
    __syncthreads();
    if (tid < 64) {
      float s = red[tid] + red[tid + 64] + red[tid + 128] + red[tid + 192];
      for (int off = 32; off > 0; off >>= 1) s += __shfl_down(s, off, 64);
      if (tid == 0) redv[0] = s * (1.f / 256.f);
    }
    __syncthreads();
    float mu = redv[0];
    if (tid < 256) red[tid] = (hv - mu) * (hv - mu);
    __syncthreads();
    if (tid < 64) {
      float s = red[tid] + red[tid + 64] + red[tid + 128] + red[tid + 192];
      for (int off = 32; off > 0; off >>= 1) s += __shfl_down(s, off, 64);
      if (tid == 0) redv[1] = s * (1.f / 256.f);
    }
    __syncthreads();
    if (tid < 256)   // both sides write identical values (benign)
      out[(size_t)node * 256 + tid] =
          (hv - mu) * rsqrtf(redv[1] + 1e-5f) * gamma[tid] + beta[tid];
  }
}

extern "C" void kernel_launch(void* const* d_in, const int* in_sizes, int n_in,
                              void* d_out, int out_size, void* d_ws, size_t ws_size,
                              hipStream_t stream) {
  const float* x     = (const float*)d_in[0];
  const float* Wih0  = (const float*)d_in[1];
  const float* Whh0  = (const float*)d_in[2];
  const float* bih0  = (const float*)d_in[3];
  const float* bhh0  = (const float*)d_in[4];
  const float* Wih1  = (const float*)d_in[5];
  const float* Whh1  = (const float*)d_in[6];
  const float* bih1  = (const float*)d_in[7];
  const float* bhh1  = (const float*)d_in[8];
  const float* gamma = (const float*)d_in[9];
  const float* beta  = (const float*)d_in[10];
  float* out = (float*)d_out;

  unsigned short* xw  = (unsigned short*)d_ws;                              // 128 MiB
  unsigned short* hs0 = (unsigned short*)((char*)d_ws + (size_t)134217728); // 32 MiB
  // exchange + flags carved from the end of ws (needs ws >= 160 MiB + ~132 KiB)
  size_t tailOff = (ws_size - (size_t)(134 * 1024)) & ~(size_t)255;
  unsigned* exch = (unsigned*)((char*)d_ws + tailOff);   // 128 KiB
  int* flags = (int*)((char*)d_ws + tailOff + 131072);   // 2 KiB (both layers)
  hipMemsetAsync(flags, 0, 2048, stream);

  gemm_xw<32, 32, false><<<dim3(32, 128), 256, 0, stream>>>(x, Wih0, xw);
  lstm_rec<true, false><<<256, 512, 0, stream>>>(xw, Whh0, bih0, bhh0, hs0,
                                                 nullptr, nullptr, nullptr,
                                                 exch, flags);
  gemm_xw<256, 128, true><<<dim3(32, 128), 256, 0, stream>>>(hs0, Wih1, xw);
  lstm_rec<false, true><<<256, 512, 0, stream>>>(xw, Whh1, bih1, bhh1, nullptr,
                                                 gamma, beta, out,
                                                 exch, flags + 256);
}